// Round 1
// baseline (299.956 us; speedup 1.0000x reference)
//
#include <hip/hip_runtime.h>
#include <hip/hip_bf16.h>

// FourierResistor: B=8, N=4096, d=128, H=4, fp32.
// Decomposition: "ones(N,N)-I" contractions are sum-minus-self ->
//   f[k,b,n,d]  = S[k,b,d] - xe[k,b,n,d],  S = sum_n xe
//   inv[b,n,h,d]= (T[b,h,d] - rfe[b,n,h,d]) / N,  T = sum_n rfe
// Pipeline:
//   K1 gemm: x1 = x @ W_lt^T                    (fp32)
//   K2     : S0[b,d]=sum x1*c, S1[b,d]=sum x1*s (atomics)
//   K3 gemm: phi = (x1+pos) @ W_phi^T + b_phi   (bf16 out, 4 col-tiles)
//   K4     : T[b,h,d] = sum_n rfe (recomputed)  (atomics)
//   K5     : comb MLP + m=x1+comb + LayerNorm -> mn
//   K6 gemm: h1 = relu(mn @ W_f1^T + b_f1)      (h1 aliases x1 buffer)
//   K7 gemm: out = h1 @ W_f2^T + b_f2
// ws usage ~67.2 MB.

#define DEV __device__ __forceinline__

constexpr int Bb = 8, Nn = 4096, Dd = 128, Hh = 4;
constexpr int BN = Bb * Nn; // 32768

static DEV unsigned short f2bf_bits(float f) {
    __hip_bfloat16 h = __float2bfloat16(f);
    return *reinterpret_cast<unsigned short*>(&h);
}

// ---------------------------------------------------------------------------
// Generic 128-K GEMM: out[r,j] = act( X[r,:] (+pos) ) dot W[j,:] + bias
// MODE 0: x1 = x @ Wlt^T              (f32 out, no bias)
// MODE 1: phi = (x1+pos) @ Wphi^T + b (bf16 out, blockIdx.y = col tile of 128)
// MODE 2: h1 = relu(mn @ Wf1^T + b)   (f32 out)
// MODE 3: out = h1 @ Wf2^T + b        (f32 out)
// Block: 256 thr, 64 rows x 128 cols, micro-tile 8 rows x 4 cols.
// ---------------------------------------------------------------------------
template <int MODE>
__global__ __launch_bounds__(256) void k_gemm128(
    const float* __restrict__ X, const float* __restrict__ W,
    const float* __restrict__ bias, const float* __restrict__ pos,
    float* __restrict__ outF, __hip_bfloat16* __restrict__ outB)
{
    __shared__ __align__(16) float xs[64 * 128];   // 32 KB
    __shared__ __align__(16) float wsh[64 * 128];  // 32 KB (one K-half of W)

    const int t  = threadIdx.x;
    const int tx = t & 31;   // col group: cols 4*tx..4*tx+3
    const int ty = t >> 5;   // row group: rows ty*8..ty*8+7
    const int row0 = blockIdx.x * 64;
    const int jt = (MODE == 1) ? blockIdx.y : 0;
    const float* Wt = W + (size_t)jt * 128 * 128;

    // stage X tile (64 rows x 128 cols)
    #pragma unroll
    for (int i = 0; i < 8; ++i) {
        int e = t + i * 256;          // float4 index, 0..2047
        int r = e >> 5, c4 = e & 31;
        float4 v = *reinterpret_cast<const float4*>(X + (size_t)(row0 + r) * 128 + c4 * 4);
        if (MODE == 1) {
            int n = (row0 + r) & (Nn - 1);
            float4 p = *reinterpret_cast<const float4*>(pos + (size_t)n * 128 + c4 * 4);
            v.x += p.x; v.y += p.y; v.z += p.z; v.w += p.w;
        }
        *reinterpret_cast<float4*>(xs + e * 4) = v;
    }

    float acc[8][4];
    #pragma unroll
    for (int rr = 0; rr < 8; ++rr)
        #pragma unroll
        for (int jj = 0; jj < 4; ++jj) acc[rr][jj] = 0.f;

    for (int half = 0; half < 2; ++half) {
        __syncthreads();  // protect wsh reuse (and xs before first compute)
        // stage W K-half transposed: wsh[k_local*128 + j] = W[j][half*64+k_local]
        #pragma unroll
        for (int i = 0; i < 8; ++i) {
            int e = t + i * 256;      // float4 index over [128 j][16 k4]
            int j = e >> 4, k4 = e & 15;
            float4 v = *reinterpret_cast<const float4*>(Wt + (size_t)j * 128 + half * 64 + k4 * 4);
            wsh[(k4 * 4 + 0) * 128 + j] = v.x;
            wsh[(k4 * 4 + 1) * 128 + j] = v.y;
            wsh[(k4 * 4 + 2) * 128 + j] = v.z;
            wsh[(k4 * 4 + 3) * 128 + j] = v.w;
        }
        __syncthreads();

        #pragma unroll 4
        for (int k4 = 0; k4 < 16; ++k4) {
            float4 w0 = *reinterpret_cast<const float4*>(wsh + (k4 * 4 + 0) * 128 + tx * 4);
            float4 w1 = *reinterpret_cast<const float4*>(wsh + (k4 * 4 + 1) * 128 + tx * 4);
            float4 w2 = *reinterpret_cast<const float4*>(wsh + (k4 * 4 + 2) * 128 + tx * 4);
            float4 w3 = *reinterpret_cast<const float4*>(wsh + (k4 * 4 + 3) * 128 + tx * 4);
            #pragma unroll
            for (int rr = 0; rr < 8; ++rr) {
                float4 xv = *reinterpret_cast<const float4*>(xs + (ty * 8 + rr) * 128 + (half * 16 + k4) * 4);
                acc[rr][0] += xv.x * w0.x + xv.y * w1.x + xv.z * w2.x + xv.w * w3.x;
                acc[rr][1] += xv.x * w0.y + xv.y * w1.y + xv.z * w2.y + xv.w * w3.y;
                acc[rr][2] += xv.x * w0.z + xv.y * w1.z + xv.z * w2.z + xv.w * w3.z;
                acc[rr][3] += xv.x * w0.w + xv.y * w1.w + xv.z * w2.w + xv.w * w3.w;
            }
        }
    }

    // epilogue
    float4 bv = make_float4(0.f, 0.f, 0.f, 0.f);
    if (MODE >= 1) bv = *reinterpret_cast<const float4*>(bias + jt * 128 + tx * 4);
    #pragma unroll
    for (int rr = 0; rr < 8; ++rr) {
        int r = row0 + ty * 8 + rr;
        float4 o = make_float4(acc[rr][0] + bv.x, acc[rr][1] + bv.y,
                               acc[rr][2] + bv.z, acc[rr][3] + bv.w);
        if (MODE == 2) {
            o.x = fmaxf(o.x, 0.f); o.y = fmaxf(o.y, 0.f);
            o.z = fmaxf(o.z, 0.f); o.w = fmaxf(o.w, 0.f);
        }
        if (MODE == 1) {
            ushort4 u;
            u.x = f2bf_bits(o.x); u.y = f2bf_bits(o.y);
            u.z = f2bf_bits(o.z); u.w = f2bf_bits(o.w);
            *reinterpret_cast<ushort4*>(outB + (size_t)r * 512 + jt * 128 + tx * 4) = u;
        } else {
            *reinterpret_cast<float4*>(outF + (size_t)r * 128 + tx * 4) = o;
        }
    }
}

// ---------------------------------------------------------------------------
// K2: S0[b,d] = sum_n x1[b,n,d]*c[n,d], S1[b,d] = sum_n x1[b,n,d]*s[n,d]
//     c[n,d]=pos[n,d|1], s[n,d]=pos[n,d&~1]
// ---------------------------------------------------------------------------
__global__ __launch_bounds__(256) void k_reduceS(
    const float* __restrict__ x1, const float* __restrict__ pos,
    float* __restrict__ S0, float* __restrict__ S1)
{
    int b = blockIdx.x >> 3, chunk = blockIdx.x & 7;
    int d = threadIdx.x & 127, g = threadIdx.x >> 7;
    float a0 = 0.f, a1 = 0.f;
    for (int i = 0; i < 256; ++i) {
        int n = chunk * 512 + g + 2 * i;
        float xv = x1[((size_t)b * Nn + n) * 128 + d];
        float2 p2 = *reinterpret_cast<const float2*>(pos + (size_t)n * 128 + (d & ~1));
        a0 += xv * p2.y;  // c
        a1 += xv * p2.x;  // s
    }
    atomicAdd(&S0[b * 128 + d], a0);
    atomicAdd(&S1[b * 128 + d], a1);
}

// ---------------------------------------------------------------------------
// K4: T[b,h,d] = sum_n rfe[b,n,h,d], rfe recomputed from x1, phi, S
// ---------------------------------------------------------------------------
__global__ __launch_bounds__(256) void k_reduceT(
    const float* __restrict__ x1, const __hip_bfloat16* __restrict__ phi,
    const float* __restrict__ pos, const float* __restrict__ S0,
    const float* __restrict__ S1, float* __restrict__ T)
{
    int b = blockIdx.x >> 4, chunk = blockIdx.x & 15;
    int d = threadIdx.x & 127, g = threadIdx.x >> 7;
    float S0v = S0[b * 128 + d], S1v = S1[b * 128 + d];
    float acc[4] = {0.f, 0.f, 0.f, 0.f};
    for (int i = 0; i < 128; ++i) {
        int n = chunk * 256 + g + 2 * i;
        size_t r = (size_t)b * Nn + n;
        float xv = x1[r * 128 + d];
        float2 p2 = *reinterpret_cast<const float2*>(pos + (size_t)n * 128 + (d & ~1));
        float cc = p2.y, ss = p2.x;
        float f0 = S0v - xv * cc;
        float f1 = xv * ss - S1v;
        float fn = sqrtf(f0 * f0 + f1 * f1);
        float fec = f0 * cc - f1 * ss;
        #pragma unroll
        for (int h = 0; h < 4; ++h) {
            float ph = __bfloat162float(phi[r * 512 + h * 128 + d]);
            float res = fmaxf(0.f, fminf(1.f, fn - ph));
            acc[h] += res * fec;
        }
    }
    #pragma unroll
    for (int h = 0; h < 4; ++h) atomicAdd(&T[(b * 4 + h) * 128 + d], acc[h]);
}

// ---------------------------------------------------------------------------
// K5: per row: inv -> comb MLP -> m = x1+comb -> LayerNorm -> mn
// block = 256 thr = 4 waves, one wave per row, lane l covers d=l and d=l+64
// ---------------------------------------------------------------------------
__global__ __launch_bounds__(256) void k_comb_ln(
    const float* __restrict__ x1, const __hip_bfloat16* __restrict__ phi,
    const float* __restrict__ pos, const float* __restrict__ S0,
    const float* __restrict__ S1, const float* __restrict__ T,
    const float* __restrict__ Wc1, const float* __restrict__ bc1,
    const float* __restrict__ Wc2, const float* __restrict__ bc2,
    const float* __restrict__ lng, const float* __restrict__ lnb,
    float* __restrict__ mn)
{
    int w = threadIdx.x >> 6, l = threadIdx.x & 63;
    int rrow = blockIdx.x * 4 + w;
    int b = rrow >> 12;
    int n = rrow & 4095;

    float m[2];
    #pragma unroll
    for (int q = 0; q < 2; ++q) {
        int d = l + q * 64;
        float xv = x1[(size_t)rrow * 128 + d];
        float2 p2 = *reinterpret_cast<const float2*>(pos + (size_t)n * 128 + (d & ~1));
        float cc = p2.y, ss = p2.x;
        float f0 = S0[b * 128 + d] - xv * cc;
        float f1 = xv * ss - S1[b * 128 + d];
        float fn = sqrtf(f0 * f0 + f1 * f1);
        float fec = f0 * cc - f1 * ss;
        float inv[4];
        #pragma unroll
        for (int h = 0; h < 4; ++h) {
            float ph = __bfloat162float(phi[(size_t)rrow * 512 + h * 128 + d]);
            float res = fmaxf(0.f, fminf(1.f, fn - ph));
            float rfe = res * fec;
            inv[h] = (T[(b * 4 + h) * 128 + d] - rfe) * (1.f / (float)Nn);
        }
        float comb = bc2[0];
        #pragma unroll
        for (int h = 0; h < 4; ++h) {
            float u = bc1[h];
            #pragma unroll
            for (int h2 = 0; h2 < 4; ++h2) u += Wc1[h * 4 + h2] * inv[h2];
            comb += fmaxf(u, 0.f) * Wc2[h];
        }
        m[q] = xv + comb;
    }

    float s = m[0] + m[1];
    #pragma unroll
    for (int off = 32; off; off >>= 1) s += __shfl_xor(s, off);
    float mu = s * (1.f / 128.f);
    float d0 = m[0] - mu, d1 = m[1] - mu;
    float v = d0 * d0 + d1 * d1;
    #pragma unroll
    for (int off = 32; off; off >>= 1) v += __shfl_xor(v, off);
    float rstd = rsqrtf(v * (1.f / 128.f) + 1e-6f);
    mn[(size_t)rrow * 128 + l]      = d0 * rstd * lng[l] + lnb[l];
    mn[(size_t)rrow * 128 + l + 64] = d1 * rstd * lng[l + 64] + lnb[l + 64];
}

// ---------------------------------------------------------------------------
extern "C" void kernel_launch(void* const* d_in, const int* in_sizes, int n_in,
                              void* d_out, int out_size, void* d_ws, size_t ws_size,
                              hipStream_t stream)
{
    const float* x    = (const float*)d_in[0];
    const float* pos  = (const float*)d_in[1];
    const float* Wlt  = (const float*)d_in[2];
    const float* Wphi = (const float*)d_in[3];
    const float* bphi = (const float*)d_in[4];
    const float* Wc1  = (const float*)d_in[5];
    const float* bc1  = (const float*)d_in[6];
    const float* Wc2  = (const float*)d_in[7];
    const float* bc2  = (const float*)d_in[8];
    const float* lng  = (const float*)d_in[9];
    const float* lnb  = (const float*)d_in[10];
    const float* Wf1  = (const float*)d_in[11];
    const float* bf1  = (const float*)d_in[12];
    const float* Wf2  = (const float*)d_in[13];
    const float* bf2  = (const float*)d_in[14];

    float* ws = (float*)d_ws;
    float* x1 = ws;                       // [BN*128], later reused as h1
    float* mn = ws + 4194304;             // [BN*128]
    float* S0 = ws + 8388608;             // [1024]
    float* S1 = S0 + 1024;                // [1024]
    float* T  = S1 + 1024;                // [4096]
    __hip_bfloat16* phi = (__hip_bfloat16*)(ws + 8394752);  // [BN*512] bf16
    float* out = (float*)d_out;

    // zero the atomic accumulators (S0,S1,T are contiguous)
    hipMemsetAsync(S0, 0, (1024 + 1024 + 4096) * sizeof(float), stream);

    k_gemm128<0><<<dim3(BN / 64), 256, 0, stream>>>(x, Wlt, nullptr, nullptr, x1, nullptr);
    k_reduceS<<<dim3(Bb * 8), 256, 0, stream>>>(x1, pos, S0, S1);
    k_gemm128<1><<<dim3(BN / 64, 4), 256, 0, stream>>>(x1, Wphi, bphi, pos, nullptr, phi);
    k_reduceT<<<dim3(Bb * 16), 256, 0, stream>>>(x1, phi, pos, S0, S1, T);
    k_comb_ln<<<dim3(BN / 4), 256, 0, stream>>>(x1, phi, pos, S0, S1, T,
                                                Wc1, bc1, Wc2, bc2, lng, lnb, mn);
    k_gemm128<2><<<dim3(BN / 64), 256, 0, stream>>>(mn, Wf1, bf1, nullptr, x1, nullptr);
    k_gemm128<3><<<dim3(BN / 64), 256, 0, stream>>>(x1, Wf2, bf2, nullptr, out, nullptr);
}

// Round 2
// 167.352 us; speedup vs baseline: 1.7924x; 1.7924x over previous
//
#include <hip/hip_runtime.h>
#include <hip/hip_bf16.h>

// FourierResistor: B=8, N=4096, d=128, H=4, fp32 in/out.
// sum-minus-self decomposition:
//   f[k,b,n,d]  = S[k,b,d] - xe[k,b,n,d],  S = sum_n xe
//   inv[b,n,h,d]= (T[b,h,d] - rfe[b,n,h,d]) / N,  T = sum_n rfe
// Pipeline (GEMMs now MFMA bf16):
//   K1 gemm: x1 = x @ W_lt^T                    (fp32 out)
//   K2     : S0[b,d], S1[b,d] reductions        (atomics)
//   K3 gemm: phi = (x1+pos) @ W_phi^T + b_phi   (bf16 out, 4 col tiles)
//   K4     : T[b,h,d] = sum_n rfe (recomputed)  (atomics)
//   K5     : comb MLP + m=x1+comb + LayerNorm -> mn (fp32)
//   K6 gemm: h1 = relu(mn @ W_f1^T + b_f1)      (bf16 out, aliases x1)
//   K7 gemm: out = h1 @ W_f2^T + b_f2           (bf16 in, fp32 out)

#define DEV __device__ __forceinline__

typedef __attribute__((ext_vector_type(8))) short bf16x8;
typedef __attribute__((ext_vector_type(4))) float f32x4;

constexpr int Bb = 8, Nn = 4096;
constexpr int BN = Bb * Nn;     // 32768
constexpr int LDP = 136;        // padded LDS pitch in bf16 elems (272 B)

union U8 { ushort u[8]; uint4 v; };

static DEV ushort f2bf(float f) {
    __hip_bfloat16 h = __float2bfloat16(f);
    return *reinterpret_cast<ushort*>(&h);
}

// ---------------------------------------------------------------------------
// MFMA GEMM, K=128, out tile 64 rows x 128 cols, 256 thr (4 waves x 16 rows).
// MODE 0: x1 = x @ Wlt^T              (f32 in,  f32 out, no bias)
// MODE 1: phi = (x1+pos) @ Wphi^T + b (f32 in,  bf16 out, blockIdx.y col tile)
// MODE 2: h1 = relu(mn @ Wf1^T + b)   (f32 in,  bf16 out)
// MODE 3: out = h1 @ Wf2^T + b        (bf16 in, f32 out)
// ---------------------------------------------------------------------------
template <int MODE>
__global__ __launch_bounds__(256) void k_mfma_gemm(
    const void* __restrict__ Xv, const float* __restrict__ W,
    const float* __restrict__ bias, const float* __restrict__ pos,
    float* __restrict__ outF, ushort* __restrict__ outB)
{
    __shared__ __align__(16) ushort xs[64 * LDP];    // 17 KB
    __shared__ __align__(16) ushort wsl[128 * LDP];  // 34 KB
    const int t = threadIdx.x;
    const int row0 = blockIdx.x * 64;
    const int jt = (MODE == 1) ? blockIdx.y : 0;

    // ---- stage X tile (64 rows x 128), convert to bf16 ----
    if (MODE == 3) {
        const ushort* X = (const ushort*)Xv;
        #pragma unroll
        for (int i = 0; i < 4; ++i) {
            int e = t + i * 256, r = e >> 4, c = (e & 15) * 8;
            uint4 v = *reinterpret_cast<const uint4*>(X + (size_t)(row0 + r) * 128 + c);
            *reinterpret_cast<uint4*>(xs + r * LDP + c) = v;
        }
    } else {
        const float* X = (const float*)Xv;
        #pragma unroll
        for (int i = 0; i < 4; ++i) {
            int e = t + i * 256, r = e >> 4, c = (e & 15) * 8;
            const float* p = X + (size_t)(row0 + r) * 128 + c;
            float4 a = *reinterpret_cast<const float4*>(p);
            float4 b = *reinterpret_cast<const float4*>(p + 4);
            if (MODE == 1) {
                int n = (row0 + r) & (Nn - 1);
                const float* q = pos + (size_t)n * 128 + c;
                float4 pa = *reinterpret_cast<const float4*>(q);
                float4 pb = *reinterpret_cast<const float4*>(q + 4);
                a.x += pa.x; a.y += pa.y; a.z += pa.z; a.w += pa.w;
                b.x += pb.x; b.y += pb.y; b.z += pb.z; b.w += pb.w;
            }
            U8 u;
            u.u[0] = f2bf(a.x); u.u[1] = f2bf(a.y); u.u[2] = f2bf(a.z); u.u[3] = f2bf(a.w);
            u.u[4] = f2bf(b.x); u.u[5] = f2bf(b.y); u.u[6] = f2bf(b.z); u.u[7] = f2bf(b.w);
            *reinterpret_cast<uint4*>(xs + r * LDP + c) = u.v;
        }
    }
    // ---- stage W col-tile (128 rows x 128), convert to bf16 ----
    {
        const float* Wt = W + (size_t)jt * 128 * 128;
        #pragma unroll
        for (int i = 0; i < 8; ++i) {
            int e = t + i * 256, r = e >> 4, c = (e & 15) * 8;
            const float* p = Wt + (size_t)r * 128 + c;
            float4 a = *reinterpret_cast<const float4*>(p);
            float4 b = *reinterpret_cast<const float4*>(p + 4);
            U8 u;
            u.u[0] = f2bf(a.x); u.u[1] = f2bf(a.y); u.u[2] = f2bf(a.z); u.u[3] = f2bf(a.w);
            u.u[4] = f2bf(b.x); u.u[5] = f2bf(b.y); u.u[6] = f2bf(b.z); u.u[7] = f2bf(b.w);
            *reinterpret_cast<uint4*>(wsl + r * LDP + c) = u.v;
        }
    }
    __syncthreads();

    const int w = t >> 6, l = t & 63;
    const int lr = l & 15;            // row within 16-frag / col within 16-frag
    const int lk = (l >> 4) * 8;      // k offset within 32-wide k-step

    f32x4 acc[8];
    #pragma unroll
    for (int cf = 0; cf < 8; ++cf) acc[cf] = f32x4{0.f, 0.f, 0.f, 0.f};

    #pragma unroll
    for (int ks = 0; ks < 4; ++ks) {
        bf16x8 a = *reinterpret_cast<const bf16x8*>(xs + (w * 16 + lr) * LDP + ks * 32 + lk);
        #pragma unroll
        for (int cf = 0; cf < 8; ++cf) {
            bf16x8 b = *reinterpret_cast<const bf16x8*>(wsl + (cf * 16 + lr) * LDP + ks * 32 + lk);
            acc[cf] = __builtin_amdgcn_mfma_f32_16x16x32_bf16(a, b, acc[cf], 0, 0, 0);
        }
    }

    // ---- epilogue: C/D layout col=lane&15, row=(lane>>4)*4+reg ----
    #pragma unroll
    for (int cf = 0; cf < 8; ++cf) {
        int col = cf * 16 + lr;
        float bv = (MODE >= 1) ? bias[jt * 128 + col] : 0.f;
        #pragma unroll
        for (int reg = 0; reg < 4; ++reg) {
            int r = row0 + w * 16 + (l >> 4) * 4 + reg;
            float o = acc[cf][reg] + bv;
            if (MODE == 2) o = fmaxf(o, 0.f);
            if (MODE == 1)      outB[(size_t)r * 512 + jt * 128 + col] = f2bf(o);
            else if (MODE == 2) outB[(size_t)r * 128 + col] = f2bf(o);
            else                outF[(size_t)r * 128 + col] = o;
        }
    }
}

// ---------------------------------------------------------------------------
// K2: S0[b,d] = sum_n x1*c, S1[b,d] = sum_n x1*s;  c=pos[n,d|1], s=pos[n,d&~1]
// ---------------------------------------------------------------------------
__global__ __launch_bounds__(256) void k_reduceS(
    const float* __restrict__ x1, const float* __restrict__ pos,
    float* __restrict__ S0, float* __restrict__ S1)
{
    int b = blockIdx.x >> 3, chunk = blockIdx.x & 7;
    int d = threadIdx.x & 127, g = threadIdx.x >> 7;
    float a0 = 0.f, a1 = 0.f;
    for (int i = 0; i < 256; ++i) {
        int n = chunk * 512 + g + 2 * i;
        float xv = x1[((size_t)b * Nn + n) * 128 + d];
        float2 p2 = *reinterpret_cast<const float2*>(pos + (size_t)n * 128 + (d & ~1));
        a0 += xv * p2.y;
        a1 += xv * p2.x;
    }
    atomicAdd(&S0[b * 128 + d], a0);
    atomicAdd(&S1[b * 128 + d], a1);
}

// ---------------------------------------------------------------------------
// K4: T[b,h,d] = sum_n rfe[b,n,h,d], rfe recomputed from x1, phi, S
// ---------------------------------------------------------------------------
__global__ __launch_bounds__(256) void k_reduceT(
    const float* __restrict__ x1, const __hip_bfloat16* __restrict__ phi,
    const float* __restrict__ pos, const float* __restrict__ S0,
    const float* __restrict__ S1, float* __restrict__ T)
{
    int b = blockIdx.x >> 4, chunk = blockIdx.x & 15;
    int d = threadIdx.x & 127, g = threadIdx.x >> 7;
    float S0v = S0[b * 128 + d], S1v = S1[b * 128 + d];
    float acc[4] = {0.f, 0.f, 0.f, 0.f};
    for (int i = 0; i < 128; ++i) {
        int n = chunk * 256 + g + 2 * i;
        size_t r = (size_t)b * Nn + n;
        float xv = x1[r * 128 + d];
        float2 p2 = *reinterpret_cast<const float2*>(pos + (size_t)n * 128 + (d & ~1));
        float cc = p2.y, ss = p2.x;
        float f0 = S0v - xv * cc;
        float f1 = xv * ss - S1v;
        float fn = sqrtf(f0 * f0 + f1 * f1);
        float fec = f0 * cc - f1 * ss;
        #pragma unroll
        for (int h = 0; h < 4; ++h) {
            float ph = __bfloat162float(phi[r * 512 + h * 128 + d]);
            float res = fmaxf(0.f, fminf(1.f, fn - ph));
            acc[h] += res * fec;
        }
    }
    #pragma unroll
    for (int h = 0; h < 4; ++h) atomicAdd(&T[(b * 4 + h) * 128 + d], acc[h]);
}

// ---------------------------------------------------------------------------
// K5: per row: inv -> comb MLP -> m = x1+comb -> LayerNorm -> mn (fp32)
// ---------------------------------------------------------------------------
__global__ __launch_bounds__(256) void k_comb_ln(
    const float* __restrict__ x1, const __hip_bfloat16* __restrict__ phi,
    const float* __restrict__ pos, const float* __restrict__ S0,
    const float* __restrict__ S1, const float* __restrict__ T,
    const float* __restrict__ Wc1, const float* __restrict__ bc1,
    const float* __restrict__ Wc2, const float* __restrict__ bc2,
    const float* __restrict__ lng, const float* __restrict__ lnb,
    float* __restrict__ mn)
{
    int w = threadIdx.x >> 6, l = threadIdx.x & 63;
    int rrow = blockIdx.x * 4 + w;
    int b = rrow >> 12;
    int n = rrow & 4095;

    float m[2];
    #pragma unroll
    for (int q = 0; q < 2; ++q) {
        int d = l + q * 64;
        float xv = x1[(size_t)rrow * 128 + d];
        float2 p2 = *reinterpret_cast<const float2*>(pos + (size_t)n * 128 + (d & ~1));
        float cc = p2.y, ss = p2.x;
        float f0 = S0[b * 128 + d] - xv * cc;
        float f1 = xv * ss - S1[b * 128 + d];
        float fn = sqrtf(f0 * f0 + f1 * f1);
        float fec = f0 * cc - f1 * ss;
        float inv[4];
        #pragma unroll
        for (int h = 0; h < 4; ++h) {
            float ph = __bfloat162float(phi[(size_t)rrow * 512 + h * 128 + d]);
            float res = fmaxf(0.f, fminf(1.f, fn - ph));
            float rfe = res * fec;
            inv[h] = (T[(b * 4 + h) * 128 + d] - rfe) * (1.f / (float)Nn);
        }
        float comb = bc2[0];
        #pragma unroll
        for (int h = 0; h < 4; ++h) {
            float u = bc1[h];
            #pragma unroll
            for (int h2 = 0; h2 < 4; ++h2) u += Wc1[h * 4 + h2] * inv[h2];
            comb += fmaxf(u, 0.f) * Wc2[h];
        }
        m[q] = xv + comb;
    }

    float s = m[0] + m[1];
    #pragma unroll
    for (int off = 32; off; off >>= 1) s += __shfl_xor(s, off);
    float mu = s * (1.f / 128.f);
    float d0 = m[0] - mu, d1 = m[1] - mu;
    float v = d0 * d0 + d1 * d1;
    #pragma unroll
    for (int off = 32; off; off >>= 1) v += __shfl_xor(v, off);
    float rstd = rsqrtf(v * (1.f / 128.f) + 1e-6f);
    mn[(size_t)rrow * 128 + l]      = d0 * rstd * lng[l] + lnb[l];
    mn[(size_t)rrow * 128 + l + 64] = d1 * rstd * lng[l + 64] + lnb[l + 64];
}

// ---------------------------------------------------------------------------
extern "C" void kernel_launch(void* const* d_in, const int* in_sizes, int n_in,
                              void* d_out, int out_size, void* d_ws, size_t ws_size,
                              hipStream_t stream)
{
    const float* x    = (const float*)d_in[0];
    const float* pos  = (const float*)d_in[1];
    const float* Wlt  = (const float*)d_in[2];
    const float* Wphi = (const float*)d_in[3];
    const float* bphi = (const float*)d_in[4];
    const float* Wc1  = (const float*)d_in[5];
    const float* bc1  = (const float*)d_in[6];
    const float* Wc2  = (const float*)d_in[7];
    const float* bc2  = (const float*)d_in[8];
    const float* lng  = (const float*)d_in[9];
    const float* lnb  = (const float*)d_in[10];
    const float* Wf1  = (const float*)d_in[11];
    const float* bf1  = (const float*)d_in[12];
    const float* Wf2  = (const float*)d_in[13];
    const float* bf2  = (const float*)d_in[14];

    float* ws = (float*)d_ws;
    float* x1 = ws;                       // [BN*128] f32, later reused as h1 (bf16)
    float* mn = ws + 4194304;             // [BN*128] f32
    float* S0 = ws + 8388608;             // [1024]
    float* S1 = S0 + 1024;                // [1024]
    float* T  = S1 + 1024;                // [4096]
    ushort* phi = (ushort*)(ws + 8394752);  // [BN*512] bf16
    ushort* h1  = (ushort*)x1;              // [BN*128] bf16 (aliases dead x1)
    float* out = (float*)d_out;

    hipMemsetAsync(S0, 0, (1024 + 1024 + 4096) * sizeof(float), stream);

    k_mfma_gemm<0><<<dim3(BN / 64), 256, 0, stream>>>(x, Wlt, nullptr, nullptr, x1, nullptr);
    k_reduceS<<<dim3(Bb * 8), 256, 0, stream>>>(x1, pos, S0, S1);
    k_mfma_gemm<1><<<dim3(BN / 64, 4), 256, 0, stream>>>(x1, Wphi, bphi, pos, nullptr, phi);
    k_reduceT<<<dim3(Bb * 16), 256, 0, stream>>>(x1, (const __hip_bfloat16*)phi, pos, S0, S1, T);
    k_comb_ln<<<dim3(BN / 4), 256, 0, stream>>>(x1, (const __hip_bfloat16*)phi, pos, S0, S1, T,
                                                Wc1, bc1, Wc2, bc2, lng, lnb, mn);
    k_mfma_gemm<2><<<dim3(BN / 64), 256, 0, stream>>>(mn, Wf1, bf1, nullptr, nullptr, h1);
    k_mfma_gemm<3><<<dim3(BN / 64), 256, 0, stream>>>(h1, Wf2, bf2, nullptr, out, nullptr);
}

// Round 3
// 83.386 us; speedup vs baseline: 3.5972x; 2.0070x over previous
//
#include <hip/hip_runtime.h>
#include <hip/hip_bf16.h>

// FourierResistor: B=8, N=4096, d=128, H=4, fp32 in/out.
// sum-minus-self decomposition:
//   f[k,b,n,d]  = S[k,b,d] - xe[k,b,n,d],  S = sum_n xe
//   inv[b,n,h,d]= (T[b,h,d] - rfe[b,n,h,d]) / N,  T = sum_n rfe
// Pipeline:
//   K1 gemm: x1 = x @ W_lt^T                    (fp32 out, MFMA bf16)
//   K2     : S0[b,d], S1[b,d] reductions        (512 blocks, BW-bound)
//   K3 gemm: phi = (x1+pos) @ W_phi^T + b_phi   (bf16 out, 4 col tiles)
//   K4     : T[b,h,d] = sum_n rfe (recomputed)  (512 blocks, BW-bound)
//   K5     : comb MLP + m=x1+comb + LN -> mn    (bf16 out)
//   K6     : out = relu(mn@Wf1^T+b)@Wf2^T + b   (fused FFN, one kernel)

#define DEV __device__ __forceinline__

typedef __attribute__((ext_vector_type(8))) short bf16x8;
typedef __attribute__((ext_vector_type(4))) float f32x4;

constexpr int Bb = 8, Nn = 4096;
constexpr int BN = Bb * Nn;     // 32768
constexpr int LDP = 136;        // padded LDS pitch in bf16 elems (272 B)

union U8 { ushort u[8]; uint4 v; };

static DEV ushort f2bf(float f) {
    __hip_bfloat16 h = __float2bfloat16(f);
    return *reinterpret_cast<ushort*>(&h);
}

// ---------------------------------------------------------------------------
// MFMA GEMM, K=128, out tile 64 rows x 128 cols, 256 thr (4 waves x 16 rows).
// MODE 0: x1 = x @ Wlt^T              (f32 in,  f32 out, no bias)
// MODE 1: phi = (x1+pos) @ Wphi^T + b (f32 in,  bf16 out, blockIdx.y col tile)
// ---------------------------------------------------------------------------
template <int MODE>
__global__ __launch_bounds__(256) void k_mfma_gemm(
    const void* __restrict__ Xv, const float* __restrict__ W,
    const float* __restrict__ bias, const float* __restrict__ pos,
    float* __restrict__ outF, ushort* __restrict__ outB)
{
    __shared__ __align__(16) ushort xs[64 * LDP];    // 17 KB
    __shared__ __align__(16) ushort wsl[128 * LDP];  // 34 KB
    const int t = threadIdx.x;
    const int row0 = blockIdx.x * 64;
    const int jt = (MODE == 1) ? blockIdx.y : 0;

    {   // stage X tile (64 rows x 128), fp32 -> bf16
        const float* X = (const float*)Xv;
        #pragma unroll
        for (int i = 0; i < 4; ++i) {
            int e = t + i * 256, r = e >> 4, c = (e & 15) * 8;
            const float* p = X + (size_t)(row0 + r) * 128 + c;
            float4 a = *reinterpret_cast<const float4*>(p);
            float4 b = *reinterpret_cast<const float4*>(p + 4);
            if (MODE == 1) {
                int n = (row0 + r) & (Nn - 1);
                const float* q = pos + (size_t)n * 128 + c;
                float4 pa = *reinterpret_cast<const float4*>(q);
                float4 pb = *reinterpret_cast<const float4*>(q + 4);
                a.x += pa.x; a.y += pa.y; a.z += pa.z; a.w += pa.w;
                b.x += pb.x; b.y += pb.y; b.z += pb.z; b.w += pb.w;
            }
            U8 u;
            u.u[0] = f2bf(a.x); u.u[1] = f2bf(a.y); u.u[2] = f2bf(a.z); u.u[3] = f2bf(a.w);
            u.u[4] = f2bf(b.x); u.u[5] = f2bf(b.y); u.u[6] = f2bf(b.z); u.u[7] = f2bf(b.w);
            *reinterpret_cast<uint4*>(xs + r * LDP + c) = u.v;
        }
    }
    {   // stage W col-tile (128 rows x 128), fp32 -> bf16
        const float* Wt = W + (size_t)jt * 128 * 128;
        #pragma unroll
        for (int i = 0; i < 8; ++i) {
            int e = t + i * 256, r = e >> 4, c = (e & 15) * 8;
            const float* p = Wt + (size_t)r * 128 + c;
            float4 a = *reinterpret_cast<const float4*>(p);
            float4 b = *reinterpret_cast<const float4*>(p + 4);
            U8 u;
            u.u[0] = f2bf(a.x); u.u[1] = f2bf(a.y); u.u[2] = f2bf(a.z); u.u[3] = f2bf(a.w);
            u.u[4] = f2bf(b.x); u.u[5] = f2bf(b.y); u.u[6] = f2bf(b.z); u.u[7] = f2bf(b.w);
            *reinterpret_cast<uint4*>(wsl + r * LDP + c) = u.v;
        }
    }
    __syncthreads();

    const int w = t >> 6, l = t & 63;
    const int lr = l & 15;
    const int lk = (l >> 4) * 8;

    f32x4 acc[8];
    #pragma unroll
    for (int cf = 0; cf < 8; ++cf) acc[cf] = f32x4{0.f, 0.f, 0.f, 0.f};

    #pragma unroll
    for (int ks = 0; ks < 4; ++ks) {
        bf16x8 a = *reinterpret_cast<const bf16x8*>(xs + (w * 16 + lr) * LDP + ks * 32 + lk);
        #pragma unroll
        for (int cf = 0; cf < 8; ++cf) {
            bf16x8 b = *reinterpret_cast<const bf16x8*>(wsl + (cf * 16 + lr) * LDP + ks * 32 + lk);
            acc[cf] = __builtin_amdgcn_mfma_f32_16x16x32_bf16(a, b, acc[cf], 0, 0, 0);
        }
    }

    // epilogue: C/D layout col=lane&15, row=(lane>>4)*4+reg
    #pragma unroll
    for (int cf = 0; cf < 8; ++cf) {
        int col = cf * 16 + lr;
        float bv = (MODE >= 1) ? bias[jt * 128 + col] : 0.f;
        #pragma unroll
        for (int reg = 0; reg < 4; ++reg) {
            int r = row0 + w * 16 + (l >> 4) * 4 + reg;
            float o = acc[cf][reg] + bv;
            if (MODE == 1) outB[(size_t)r * 512 + jt * 128 + col] = f2bf(o);
            else           outF[(size_t)r * 128 + col] = o;
        }
    }
}

// ---------------------------------------------------------------------------
// K2: S0[b,d]=sum_n x1*c, S1[b,d]=sum_n x1*s; 512 blocks x 64 rows
// ---------------------------------------------------------------------------
__global__ __launch_bounds__(256) void k_reduceS(
    const float* __restrict__ x1, const float* __restrict__ pos,
    float* __restrict__ S0, float* __restrict__ S1)
{
    int b = blockIdx.x >> 6, c64 = blockIdx.x & 63;
    int d = threadIdx.x & 127, g = threadIdx.x >> 7;
    float a0 = 0.f, a1 = 0.f;
    #pragma unroll 4
    for (int i = 0; i < 32; ++i) {
        int n = c64 * 64 + i * 2 + g;
        float xv = x1[((size_t)b * Nn + n) * 128 + d];
        float2 p2 = *reinterpret_cast<const float2*>(pos + (size_t)n * 128 + (d & ~1));
        a0 += xv * p2.y;
        a1 += xv * p2.x;
    }
    __shared__ float red[2][2][128];
    red[g][0][d] = a0; red[g][1][d] = a1;
    __syncthreads();
    if (g == 0) {
        atomicAdd(&S0[b * 128 + d], a0 + red[1][0][d]);
        atomicAdd(&S1[b * 128 + d], a1 + red[1][1][d]);
    }
}

// ---------------------------------------------------------------------------
// K4: T[b,h,d] = sum_n rfe[b,n,h,d]; 512 blocks x 64 rows
// ---------------------------------------------------------------------------
__global__ __launch_bounds__(256) void k_reduceT(
    const float* __restrict__ x1, const ushort* __restrict__ phi,
    const float* __restrict__ pos, const float* __restrict__ S0,
    const float* __restrict__ S1, float* __restrict__ T)
{
    int b = blockIdx.x >> 6, c64 = blockIdx.x & 63;
    int d = threadIdx.x & 127, g = threadIdx.x >> 7;
    float S0v = S0[b * 128 + d], S1v = S1[b * 128 + d];
    float acc[4] = {0.f, 0.f, 0.f, 0.f};
    #pragma unroll 2
    for (int i = 0; i < 32; ++i) {
        int n = c64 * 64 + i * 2 + g;
        size_t r = (size_t)b * Nn + n;
        float xv = x1[r * 128 + d];
        float2 p2 = *reinterpret_cast<const float2*>(pos + (size_t)n * 128 + (d & ~1));
        float cc = p2.y, ss = p2.x;
        float f0 = S0v - xv * cc;
        float f1 = xv * ss - S1v;
        float fn = sqrtf(f0 * f0 + f1 * f1);
        float fec = f0 * cc - f1 * ss;
        #pragma unroll
        for (int h = 0; h < 4; ++h) {
            float ph = __bfloat162float(*reinterpret_cast<const __hip_bfloat16*>(phi + r * 512 + h * 128 + d));
            float res = fmaxf(0.f, fminf(1.f, fn - ph));
            acc[h] += res * fec;
        }
    }
    __shared__ float red[2][4][128];
    #pragma unroll
    for (int h = 0; h < 4; ++h) red[g][h][d] = acc[h];
    __syncthreads();
    if (g == 0) {
        #pragma unroll
        for (int h = 0; h < 4; ++h)
            atomicAdd(&T[(b * 4 + h) * 128 + d], acc[h] + red[1][h][d]);
    }
}

// ---------------------------------------------------------------------------
// K5: per row: inv -> comb MLP -> m = x1+comb -> LayerNorm -> mn (bf16)
// ---------------------------------------------------------------------------
__global__ __launch_bounds__(256) void k_comb_ln(
    const float* __restrict__ x1, const ushort* __restrict__ phi,
    const float* __restrict__ pos, const float* __restrict__ S0,
    const float* __restrict__ S1, const float* __restrict__ T,
    const float* __restrict__ Wc1, const float* __restrict__ bc1,
    const float* __restrict__ Wc2, const float* __restrict__ bc2,
    const float* __restrict__ lng, const float* __restrict__ lnb,
    ushort* __restrict__ mnB)
{
    int w = threadIdx.x >> 6, l = threadIdx.x & 63;
    int rrow = blockIdx.x * 4 + w;
    int b = rrow >> 12;
    int n = rrow & 4095;

    float m[2];
    #pragma unroll
    for (int q = 0; q < 2; ++q) {
        int d = l + q * 64;
        float xv = x1[(size_t)rrow * 128 + d];
        float2 p2 = *reinterpret_cast<const float2*>(pos + (size_t)n * 128 + (d & ~1));
        float cc = p2.y, ss = p2.x;
        float f0 = S0[b * 128 + d] - xv * cc;
        float f1 = xv * ss - S1[b * 128 + d];
        float fn = sqrtf(f0 * f0 + f1 * f1);
        float fec = f0 * cc - f1 * ss;
        float inv[4];
        #pragma unroll
        for (int h = 0; h < 4; ++h) {
            float ph = __bfloat162float(*reinterpret_cast<const __hip_bfloat16*>(phi + (size_t)rrow * 512 + h * 128 + d));
            float res = fmaxf(0.f, fminf(1.f, fn - ph));
            float rfe = res * fec;
            inv[h] = (T[(b * 4 + h) * 128 + d] - rfe) * (1.f / (float)Nn);
        }
        float comb = bc2[0];
        #pragma unroll
        for (int h = 0; h < 4; ++h) {
            float u = bc1[h];
            #pragma unroll
            for (int h2 = 0; h2 < 4; ++h2) u += Wc1[h * 4 + h2] * inv[h2];
            comb += fmaxf(u, 0.f) * Wc2[h];
        }
        m[q] = xv + comb;
    }

    float s = m[0] + m[1];
    #pragma unroll
    for (int off = 32; off; off >>= 1) s += __shfl_xor(s, off);
    float mu = s * (1.f / 128.f);
    float d0 = m[0] - mu, d1 = m[1] - mu;
    float v = d0 * d0 + d1 * d1;
    #pragma unroll
    for (int off = 32; off; off >>= 1) v += __shfl_xor(v, off);
    float rstd = rsqrtf(v * (1.f / 128.f) + 1e-6f);
    mnB[(size_t)rrow * 128 + l]      = f2bf(d0 * rstd * lng[l] + lnb[l]);
    mnB[(size_t)rrow * 128 + l + 64] = f2bf(d1 * rstd * lng[l + 64] + lnb[l + 64]);
}

// ---------------------------------------------------------------------------
// K6: fused FFN: out = relu(mn @ Wf1^T + b1) @ Wf2^T + b2
// ---------------------------------------------------------------------------
__global__ __launch_bounds__(256) void k_ffn(
    const ushort* __restrict__ mnB, const float* __restrict__ Wf1,
    const float* __restrict__ bf1, const float* __restrict__ Wf2,
    const float* __restrict__ bf2, float* __restrict__ out)
{
    __shared__ __align__(16) ushort xs[64 * LDP];
    __shared__ __align__(16) ushort wsl[128 * LDP];
    const int t = threadIdx.x;
    const int row0 = blockIdx.x * 64;

    // stage mn (bf16 passthrough)
    #pragma unroll
    for (int i = 0; i < 4; ++i) {
        int e = t + i * 256, r = e >> 4, c = (e & 15) * 8;
        uint4 v = *reinterpret_cast<const uint4*>(mnB + (size_t)(row0 + r) * 128 + c);
        *reinterpret_cast<uint4*>(xs + r * LDP + c) = v;
    }
    // stage Wf1
    #pragma unroll
    for (int i = 0; i < 8; ++i) {
        int e = t + i * 256, r = e >> 4, c = (e & 15) * 8;
        const float* p = Wf1 + (size_t)r * 128 + c;
        float4 a = *reinterpret_cast<const float4*>(p);
        float4 b = *reinterpret_cast<const float4*>(p + 4);
        U8 u;
        u.u[0] = f2bf(a.x); u.u[1] = f2bf(a.y); u.u[2] = f2bf(a.z); u.u[3] = f2bf(a.w);
        u.u[4] = f2bf(b.x); u.u[5] = f2bf(b.y); u.u[6] = f2bf(b.z); u.u[7] = f2bf(b.w);
        *reinterpret_cast<uint4*>(wsl + r * LDP + c) = u.v;
    }
    __syncthreads();

    const int w = t >> 6, l = t & 63;
    const int lr = l & 15;
    const int lk = (l >> 4) * 8;

    f32x4 acc[8];
    #pragma unroll
    for (int cf = 0; cf < 8; ++cf) acc[cf] = f32x4{0.f, 0.f, 0.f, 0.f};
    #pragma unroll
    for (int ks = 0; ks < 4; ++ks) {
        bf16x8 a = *reinterpret_cast<const bf16x8*>(xs + (w * 16 + lr) * LDP + ks * 32 + lk);
        #pragma unroll
        for (int cf = 0; cf < 8; ++cf) {
            bf16x8 b = *reinterpret_cast<const bf16x8*>(wsl + (cf * 16 + lr) * LDP + ks * 32 + lk);
            acc[cf] = __builtin_amdgcn_mfma_f32_16x16x32_bf16(a, b, acc[cf], 0, 0, 0);
        }
    }

    __syncthreads();  // all MFMA reads of xs/wsl done

    // h1 = relu(acc + b1) -> back into xs (bf16)
    #pragma unroll
    for (int cf = 0; cf < 8; ++cf) {
        int col = cf * 16 + lr;
        float bv = bf1[col];
        #pragma unroll
        for (int reg = 0; reg < 4; ++reg) {
            int rl = w * 16 + (l >> 4) * 4 + reg;
            xs[rl * LDP + col] = f2bf(fmaxf(acc[cf][reg] + bv, 0.f));
        }
    }
    // restage wsl with Wf2
    #pragma unroll
    for (int i = 0; i < 8; ++i) {
        int e = t + i * 256, r = e >> 4, c = (e & 15) * 8;
        const float* p = Wf2 + (size_t)r * 128 + c;
        float4 a = *reinterpret_cast<const float4*>(p);
        float4 b = *reinterpret_cast<const float4*>(p + 4);
        U8 u;
        u.u[0] = f2bf(a.x); u.u[1] = f2bf(a.y); u.u[2] = f2bf(a.z); u.u[3] = f2bf(a.w);
        u.u[4] = f2bf(b.x); u.u[5] = f2bf(b.y); u.u[6] = f2bf(b.z); u.u[7] = f2bf(b.w);
        *reinterpret_cast<uint4*>(wsl + r * LDP + c) = u.v;
    }
    __syncthreads();

    #pragma unroll
    for (int cf = 0; cf < 8; ++cf) acc[cf] = f32x4{0.f, 0.f, 0.f, 0.f};
    #pragma unroll
    for (int ks = 0; ks < 4; ++ks) {
        bf16x8 a = *reinterpret_cast<const bf16x8*>(xs + (w * 16 + lr) * LDP + ks * 32 + lk);
        #pragma unroll
        for (int cf = 0; cf < 8; ++cf) {
            bf16x8 b = *reinterpret_cast<const bf16x8*>(wsl + (cf * 16 + lr) * LDP + ks * 32 + lk);
            acc[cf] = __builtin_amdgcn_mfma_f32_16x16x32_bf16(a, b, acc[cf], 0, 0, 0);
        }
    }

    #pragma unroll
    for (int cf = 0; cf < 8; ++cf) {
        int col = cf * 16 + lr;
        float bv = bf2[col];
        #pragma unroll
        for (int reg = 0; reg < 4; ++reg) {
            int r = row0 + w * 16 + (l >> 4) * 4 + reg;
            out[(size_t)r * 128 + col] = acc[cf][reg] + bv;
        }
    }
}

// ---------------------------------------------------------------------------
extern "C" void kernel_launch(void* const* d_in, const int* in_sizes, int n_in,
                              void* d_out, int out_size, void* d_ws, size_t ws_size,
                              hipStream_t stream)
{
    const float* x    = (const float*)d_in[0];
    const float* pos  = (const float*)d_in[1];
    const float* Wlt  = (const float*)d_in[2];
    const float* Wphi = (const float*)d_in[3];
    const float* bphi = (const float*)d_in[4];
    const float* Wc1  = (const float*)d_in[5];
    const float* bc1  = (const float*)d_in[6];
    const float* Wc2  = (const float*)d_in[7];
    const float* bc2  = (const float*)d_in[8];
    const float* lng  = (const float*)d_in[9];
    const float* lnb  = (const float*)d_in[10];
    const float* Wf1  = (const float*)d_in[11];
    const float* bf1  = (const float*)d_in[12];
    const float* Wf2  = (const float*)d_in[13];
    const float* bf2  = (const float*)d_in[14];

    float* ws = (float*)d_ws;
    float* x1 = ws;                         // [BN*128] f32
    ushort* mnB = (ushort*)(ws + 4194304);  // [BN*128] bf16
    float* S0 = ws + 8388608;               // [1024]
    float* S1 = S0 + 1024;                  // [1024]
    float* T  = S1 + 1024;                  // [4096]
    ushort* phi = (ushort*)(ws + 8394752);  // [BN*512] bf16
    float* out = (float*)d_out;

    hipMemsetAsync(S0, 0, (1024 + 1024 + 4096) * sizeof(float), stream);

    k_mfma_gemm<0><<<dim3(BN / 64), 256, 0, stream>>>(x, Wlt, nullptr, nullptr, x1, nullptr);
    k_reduceS<<<dim3(512), 256, 0, stream>>>(x1, pos, S0, S1);
    k_mfma_gemm<1><<<dim3(BN / 64, 4), 256, 0, stream>>>(x1, Wphi, bphi, pos, nullptr, phi);
    k_reduceT<<<dim3(512), 256, 0, stream>>>(x1, phi, pos, S0, S1, T);
    k_comb_ln<<<dim3(BN / 4), 256, 0, stream>>>(x1, phi, pos, S0, S1, T,
                                                Wc1, bc1, Wc2, bc2, lng, lnb, mnB);
    k_ffn<<<dim3(BN / 64), 256, 0, stream>>>(mnB, Wf1, bf1, Wf2, bf2, out);
}